// Round 10
// baseline (170.593 us; speedup 1.0000x reference)
//
#include <hip/hip_runtime.h>
#include <cfloat>

typedef __attribute__((ext_vector_type(8))) short short8;
typedef __attribute__((ext_vector_type(4))) float f32x4;

#define NE 1024
#define EDIM 256
#define HW 1024
#define BSTRIDE (EDIM * HW)        // 262144
#define TOTAL 8388608

// workspace layout (bytes)
#define EMBB_OFF  0                        // ushort[1024*256] bf16 = 512 KB
#define ENORM_OFF (512 * 1024)             // float[1024]
#define HIST_OFF  (ENORM_OFF + 4096)       // int[1024]
#define LOSS_OFF  (HIST_OFF + 4096)        // float[64] banked loss accum
#define GCNT_OFF  (LOSS_OFF + 256)         // int[512] per-group twin counter
#define GDONE_OFF (GCNT_OFF + 2048)        // int completion counter
#define BEST_OFF  (GDONE_OFF + 16)         // u64[32768] packed (dist,code)

// round-to-nearest-even fp32 -> bf16 bits (inputs are finite)
__device__ __forceinline__ unsigned short f2bf(float x) {
    unsigned u = __builtin_bit_cast(unsigned, x);
    return (unsigned short)((u + 0x7fffu + ((u >> 16) & 1u)) >> 16);
}

// async global->LDS, 16B per lane, LDS dest = uniform base + lane*16
__device__ __forceinline__ void stage16(const void* g, void* l) {
    __builtin_amdgcn_global_load_lds(
        (const __attribute__((address_space(1))) unsigned int*)g,
        (__attribute__((address_space(3))) unsigned int*)l, 16, 0, 0);
}

// ---------------------------------------------------------------------------
// P: emb fp32 [1024][256] -> embB bf16 rows + enorm. 64 blocks x 256 thr.
// Also inits best64 (all blocks) and hist/loss/gcnt/gdone (block 0).
// ---------------------------------------------------------------------------
__global__ void prep_emb(const float* __restrict__ emb,
                         unsigned short* __restrict__ embB,
                         float* __restrict__ enorm,
                         int* __restrict__ hist,
                         float* __restrict__ lossAcc,
                         int* __restrict__ gcnt,
                         int* __restrict__ gdone,
                         unsigned long long* __restrict__ best64) {
    int t = threadIdx.x;
    int gid = blockIdx.x * 256 + t;        // 0..16383
    int row = gid >> 4, seg = gid & 15;
    const float4* e4 = (const float4*)(emb + (size_t)row * EDIM) + seg * 4;
    float4 a0 = e4[0], a1 = e4[1], a2 = e4[2], a3 = e4[3];
    float s = a0.x * a0.x + a0.y * a0.y + a0.z * a0.z + a0.w * a0.w
            + a1.x * a1.x + a1.y * a1.y + a1.z * a1.z + a1.w * a1.w
            + a2.x * a2.x + a2.y * a2.y + a2.z * a2.z + a2.w * a2.w
            + a3.x * a3.x + a3.y * a3.y + a3.z * a3.z + a3.w * a3.w;
    short8 v0, v1;
    v0[0] = (short)f2bf(a0.x); v0[1] = (short)f2bf(a0.y);
    v0[2] = (short)f2bf(a0.z); v0[3] = (short)f2bf(a0.w);
    v0[4] = (short)f2bf(a1.x); v0[5] = (short)f2bf(a1.y);
    v0[6] = (short)f2bf(a1.z); v0[7] = (short)f2bf(a1.w);
    v1[0] = (short)f2bf(a2.x); v1[1] = (short)f2bf(a2.y);
    v1[2] = (short)f2bf(a2.z); v1[3] = (short)f2bf(a2.w);
    v1[4] = (short)f2bf(a3.x); v1[5] = (short)f2bf(a3.y);
    v1[6] = (short)f2bf(a3.z); v1[7] = (short)f2bf(a3.w);
    *(short8*)&embB[(size_t)row * EDIM + seg * 16]     = v0;
    *(short8*)&embB[(size_t)row * EDIM + seg * 16 + 8] = v1;
    s += __shfl_xor(s, 1, 64);
    s += __shfl_xor(s, 2, 64);
    s += __shfl_xor(s, 4, 64);
    s += __shfl_xor(s, 8, 64);
    if (seg == 0) enorm[row] = s;
    size_t b0 = (size_t)blockIdx.x * 512 + (size_t)t * 2;
    best64[b0] = ~0ULL; best64[b0 + 1] = ~0ULL;
    if (blockIdx.x == 0) {
        ((int4*)hist)[t] = (int4){0, 0, 0, 0};
        if (t < 64)  lossAcc[t] = 0.f;
        if (t < 128) ((int4*)gcnt)[t] = (int4){0, 0, 0, 0};
        if (t == 0)  gdone[0] = 0;
    }
}

// ---------------------------------------------------------------------------
// F: fused argmin GEMM (M=32768,N=1024,K=256) + gather + loss + hist.
// R9 shell (twin split, XCD pairing: FETCH 22.7MB proven) with the
// occupancy fix the whole session pointed at:
//  - launch_bounds 2nd arg IS workgroups/CU for 256-thr blocks. Every (,2)
//    round sat at 19-25% occupancy regardless of resources; (,4) rounds hit
//    35-40% but spilled (pref[8]=64 VGPR pushed the loop past the 128 cap).
//  - Staging via global_load_lds: B bytes go HBM/L2->LDS with ZERO register
//    footprint -> loop live set ~116 VGPR -> (256,4) fits -> 4 blocks/CU.
//  - LDS dest must be linear (rule 21): B tile = 32 codes x 512B unpadded,
//    XOR-swizzle pb = o ^ ((row&7)<<4) applied on the GLOBAL SOURCE address
//    and on the ds_read address (same involution).
//  - 2x16KB B buffers inside the dead As region; ONE barrier per tile:
//    barrier (drains stage nt) -> issue stage nt+1 into the buffer everyone
//    finished reading at nt-1 -> compute tile nt. Stage flies under compute.
//  - Loss = sum(||z||^2) + sum(d_min): ||z||^2 exact fp32 in the A-stage,
//    d_min unpacked exactly from best64's order-preserving map -> owner's
//    global z re-read deleted (error ~1e-8, same selected code).
// LDS ~38.5KB -> 4 blocks/CU; grid 1024 -> all blocks resident in 1 round.
// ---------------------------------------------------------------------------
__global__ __launch_bounds__(256, 4) void fused_kernel(
        const float* __restrict__ z, const float* __restrict__ emb,
        const unsigned short* __restrict__ embB, const float* __restrict__ enormG,
        float* __restrict__ zq, int* __restrict__ hist,
        float* __restrict__ lossAcc, int* __restrict__ gcnt,
        int* __restrict__ gdone, unsigned long long* __restrict__ best64,
        float* __restrict__ out) {
    // union: As 64x264 bf16 (33792 B) during A-stage; then 2 B buffers
    // of 32 codes x 512 B (2 x 16384 B) inside the same region.
    __shared__ __align__(16) unsigned char uni[33792];
    __shared__ float Ens[512];
    __shared__ float znp[4][64];
    __shared__ float zn[64];
    __shared__ float rv[2][64];
    __shared__ int   ri[2][64];
    __shared__ int   idxm[64];
    __shared__ int   amOwner, amLast;
    __shared__ float wsum[4];

    unsigned short* As = (unsigned short*)uni;

    int t = threadIdx.x;                   // 0..255
    int bid = blockIdx.x;
    int h = (bid >> 3) & 1;                // code half; twins differ by +8 -> same XCD
    int g = (bid & 7) | ((bid >> 4) << 3); // position group 0..511 (bijective)
    int m0 = g * 64;
    int b = m0 >> 10, pb = m0 & 1023;
    const float* zb  = z  + (size_t)b * BSTRIDE + pb;
    float*       zqb = zq + (size_t)b * BSTRIDE + pb;

    for (int j = t; j < 512; j += 256) Ens[j] = enormG[h * 512 + j];

    int pq = t & 15, cg = t >> 4;          // p-quad 0..15, 16-ch group 0..15
    float s0 = 0.f, s1 = 0.f, s2 = 0.f, s3 = 0.f;   // ||z||^2 partials per pos
    {   // stage A: 64 pos x 256 ch, float4 loads along p, short8 LDS writes
        const float* zp = zb + pq * 4;
#pragma unroll
        for (int hh = 0; hh < 2; ++hh) {
            float4 zv[8];
#pragma unroll
            for (int v = 0; v < 8; ++v)
                zv[v] = *(const float4*)&zp[(size_t)(cg * 16 + hh * 8 + v) * HW];
#pragma unroll
            for (int v = 0; v < 8; ++v) {
                s0 += zv[v].x * zv[v].x; s1 += zv[v].y * zv[v].y;
                s2 += zv[v].z * zv[v].z; s3 += zv[v].w * zv[v].w;
            }
#pragma unroll
            for (int j = 0; j < 4; ++j) {
                short8 w8;
#pragma unroll
                for (int v = 0; v < 8; ++v) {
                    float x = (j == 0) ? zv[v].x : (j == 1) ? zv[v].y
                            : (j == 2) ? zv[v].z : zv[v].w;
                    w8[v] = (short)f2bf(x);
                }
                *(short8*)&As[(pq * 4 + j) * 264 + cg * 16 + hh * 8] = w8;
            }
        }
    }
    int w = t >> 6, l = t & 63, lm = l & 15, q = l >> 4;
    // reduce ||z||^2 partials across the wave's 4 channel-groups
    s0 += __shfl_xor(s0, 16, 64); s0 += __shfl_xor(s0, 32, 64);
    s1 += __shfl_xor(s1, 16, 64); s1 += __shfl_xor(s1, 32, 64);
    s2 += __shfl_xor(s2, 16, 64); s2 += __shfl_xor(s2, 32, 64);
    s3 += __shfl_xor(s3, 16, 64); s3 += __shfl_xor(s3, 32, 64);
    if (l < 16) {
        znp[w][pq * 4 + 0] = s0; znp[w][pq * 4 + 1] = s1;
        znp[w][pq * 4 + 2] = s2; znp[w][pq * 4 + 3] = s3;
    }
    __syncthreads();                       // B1: As + znp complete

    int mw = w >> 1, nw = w & 1;           // mw: 32-pos half, nw: 32-code half

    short8 A[2][8];                        // all 64 pos (2 m-frags x 8 k-slices)
#pragma unroll
    for (int s = 0; s < 2; ++s)
#pragma unroll
        for (int ks = 0; ks < 8; ++ks)
            A[s][ks] = *(const short8*)&As[(mw * 32 + s * 16 + lm) * 264 + ks * 32 + q * 8];

    float bd[8]; int bi[8];
#pragma unroll
    for (int i = 0; i < 8; ++i) { bd[i] = FLT_MAX; bi[i] = 0x7fffffff; }

    __syncthreads();                       // B2: As dead; uni becomes B dbuf
    if (t < 64) zn[t] = znp[0][t] + znp[1][t] + znp[2][t] + znp[3][t];

    // --- staging address precompute (per lane) ---
    // tile = 32 rows x 512 B; wave w covers rows [w*8, w*8+8) via 4 issues
    // of 2 rows (1 KB) each. lane l writes phys byte l*16 of the window:
    // row = w*8+2i+(l>>5), pb = (l&31)*16; source logical o = pb ^ ((row&7)<<4).
    const char* eBb = (const char*)embB + (size_t)(h * 512) * 512;
    int rIn = l >> 5, poB = (l & 31) << 4;
    int sOff0 = (w * 8 + 0 + rIn) * 512 + (poB ^ (((0 + rIn) & 7) << 4));
    int sOff1 = (w * 8 + 2 + rIn) * 512 + (poB ^ (((2 + rIn) & 7) << 4));
    int sOff2 = (w * 8 + 4 + rIn) * 512 + (poB ^ (((4 + rIn) & 7) << 4));
    int sOff3 = (w * 8 + 6 + rIn) * 512 + (poB ^ (((6 + rIn) & 7) << 4));
    int lB0 = (w * 8 + 0) * 512, lB1 = (w * 8 + 2) * 512;
    int lB2 = (w * 8 + 4) * 512, lB3 = (w * 8 + 6) * 512;

    {   // stage tile 0 -> buf0
        const char* gs = eBb;
        stage16(gs + sOff0, uni + lB0); stage16(gs + sOff1, uni + lB1);
        stage16(gs + sOff2, uni + lB2); stage16(gs + sOff3, uni + lB3);
    }

    // --- swizzled ds_read bases: logical o = ks*64 + q*16 at row cl ->
    // phys = cl*512 + (o ^ ((cl&7)<<4)); split even/odd ks (bit6) ---
    int cl = nw * 16 + lm;
    int baseE = cl * 512 + ((q << 4) ^ ((cl & 3) << 4)) + ((cl & 4) << 4);
    int baseO = baseE ^ 64;

#pragma unroll 2
    for (int nt = 0; nt < 16; ++nt) {
        __syncthreads();                   // drains stage(nt); buf ready
        if (nt < 15) {                     // stage nt+1 into the idle buffer
            const char* gs = eBb + (size_t)(nt + 1) * 32 * 512;
            char* lb = (char*)uni + (size_t)((nt + 1) & 1) * 16384;
            stage16(gs + sOff0, lb + lB0); stage16(gs + sOff1, lb + lB1);
            stage16(gs + sOff2, lb + lB2); stage16(gs + sOff3, lb + lB3);
        }
        const char* Bc = (const char*)uni + (size_t)(nt & 1) * 16384;
        f32x4 a0a = {0,0,0,0}, a0b = {0,0,0,0};
        f32x4 a1a = {0,0,0,0}, a1b = {0,0,0,0};
#pragma unroll
        for (int ks = 0; ks < 8; ks += 2) {
            short8 Bv0 = *(const short8*)(Bc + baseE + (ks >> 1) * 128);
            short8 Bv1 = *(const short8*)(Bc + baseO + (ks >> 1) * 128);
            a0a = __builtin_amdgcn_mfma_f32_16x16x32_bf16(A[0][ks],     Bv0, a0a, 0, 0, 0);
            a1a = __builtin_amdgcn_mfma_f32_16x16x32_bf16(A[1][ks],     Bv0, a1a, 0, 0, 0);
            a0b = __builtin_amdgcn_mfma_f32_16x16x32_bf16(A[0][ks + 1], Bv1, a0b, 0, 0, 0);
            a1b = __builtin_amdgcn_mfma_f32_16x16x32_bf16(A[1][ks + 1], Bv1, a1b, 0, 0, 0);
        }
        float en = Ens[nt * 32 + cl];
        int code = h * 512 + nt * 32 + cl;
#pragma unroll
        for (int r = 0; r < 4; ++r) {
            float d0 = en - 2.f * (a0a[r] + a0b[r]);
            if (d0 < bd[r])     { bd[r] = d0;     bi[r] = code; }
            float d1 = en - 2.f * (a1a[r] + a1b[r]);
            if (d1 < bd[4 + r]) { bd[4 + r] = d1; bi[4 + r] = code; }
        }
    }

    // reduce across the 16 code-columns (lanes sharing q)
#pragma unroll
    for (int off = 1; off < 16; off <<= 1) {
#pragma unroll
        for (int i = 0; i < 8; ++i) {
            float od = __shfl_xor(bd[i], off, 64);
            int   oi = __shfl_xor(bi[i], off, 64);
            if (od < bd[i] || (od == bd[i] && oi < bi[i])) { bd[i] = od; bi[i] = oi; }
        }
    }
    if (lm == 0) {
#pragma unroll
        for (int s = 0; s < 2; ++s)
#pragma unroll
            for (int r = 0; r < 4; ++r) {
                int p = mw * 32 + s * 16 + q * 4 + r;
                rv[nw][p] = bd[s * 4 + r];
                ri[nw][p] = bi[s * 4 + r];
            }
    }
    __syncthreads();
    if (t < 64) {   // merge nw halves, publish to global packed argmin
        float v0 = rv[0][t]; int i0 = ri[0][t];
        float v1 = rv[1][t]; int i1 = ri[1][t];
        float v = (v1 < v0 || (v1 == v0 && i1 < i0)) ? v1 : v0;
        int bix  = (v1 < v0 || (v1 == v0 && i1 < i0)) ? i1 : i0;
        unsigned ub = __builtin_bit_cast(unsigned, v);
        ub = (ub & 0x80000000u) ? ~ub : (ub | 0x80000000u);   // order-preserving
        unsigned long long pk = ((unsigned long long)ub << 32) | (unsigned)bix;
        atomicMin(&best64[(size_t)g * 64 + t], pk);
    }
    __syncthreads();
    if (t == 0) {
        __threadfence();
        amOwner = (atomicAdd(&gcnt[g], 1) == 1);   // 2nd finisher owns epilogue
    }
    __syncthreads();
    if (!amOwner) return;

    if (t < 64) {   // winners: code + exact d (unmap), hist + loss in one pass
        unsigned long long pk = atomicAdd(&best64[(size_t)g * 64 + t], 0ULL);
        int code = (int)(pk & 0xFFFFFFFFull);
        unsigned ub = (unsigned)(pk >> 32);
        unsigned du = (ub & 0x80000000u) ? (ub & 0x7FFFFFFFu) : ~ub;   // inverse map
        float d = __builtin_bit_cast(float, du);
        idxm[t] = code;
        atomicAdd(&hist[code], 1);
        float ls = zn[t] + d;              // sum over channels of (z-e)^2
        ls += __shfl_down(ls, 32, 64); ls += __shfl_down(ls, 16, 64);
        ls += __shfl_down(ls, 8, 64);  ls += __shfl_down(ls, 4, 64);
        ls += __shfl_down(ls, 2, 64);  ls += __shfl_down(ls, 1, 64);
        if (t == 0) atomicAdd(&lossAcc[g & 63], ls);
    }
    __syncthreads();

    {   // epilogue: gather 4 emb rows x 16 ch, write z_q (no z re-read)
        int p0 = pq * 4;
        int k0 = idxm[p0], k1 = idxm[p0 + 1], k2 = idxm[p0 + 2], k3 = idxm[p0 + 3];
#pragma unroll
        for (int hh = 0; hh < 2; ++hh) {
            int cb = cg * 16 + hh * 8;
            float e0[8], e1[8], e2[8], e3[8];
            {
                const float4* a = (const float4*)(emb + (size_t)k0 * EDIM) + (cb >> 2);
                *(float4*)&e0[0] = a[0]; *(float4*)&e0[4] = a[1];
            }
            {
                const float4* a = (const float4*)(emb + (size_t)k1 * EDIM) + (cb >> 2);
                *(float4*)&e1[0] = a[0]; *(float4*)&e1[4] = a[1];
            }
            {
                const float4* a = (const float4*)(emb + (size_t)k2 * EDIM) + (cb >> 2);
                *(float4*)&e2[0] = a[0]; *(float4*)&e2[4] = a[1];
            }
            {
                const float4* a = (const float4*)(emb + (size_t)k3 * EDIM) + (cb >> 2);
                *(float4*)&e3[0] = a[0]; *(float4*)&e3[4] = a[1];
            }
#pragma unroll
            for (int v = 0; v < 8; ++v) {
                float4 qv; qv.x = e0[v]; qv.y = e1[v]; qv.z = e2[v]; qv.w = e3[v];
                *(float4*)&zqb[(size_t)(cb + v) * HW + p0] = qv;
            }
        }
    }

    // last-owner finalize
    if (t == 0) {
        __threadfence();
        amLast = (atomicAdd(gdone, 1) == 511);
    }
    __syncthreads();
    if (amLast) {
        float s = 0.f;
        for (int j = t; j < NE; j += 256) {
            float p = (float)atomicAdd(&hist[j], 0) * (1.0f / 32768.0f);
            s += p * logf(p + 1e-10f);
        }
#pragma unroll
        for (int off = 32; off; off >>= 1) s += __shfl_down(s, off, 64);
        if ((t & 63) == 0) wsum[t >> 6] = s;
        float lt = 0.f;
        if (t < 64) lt = atomicAdd(&lossAcc[t], 0.f);
#pragma unroll
        for (int off = 32; off; off >>= 1) lt += __shfl_down(lt, off, 64);
        __syncthreads();
        if (t == 0) {
            float S = wsum[0] + wsum[1] + wsum[2] + wsum[3];
            out[TOTAL]     = 1.25f * lt / (float)TOTAL;
            out[TOTAL + 1] = expf(-S);
        }
    }
}

extern "C" void kernel_launch(void* const* d_in, const int* in_sizes, int n_in,
                              void* d_out, int out_size, void* d_ws, size_t ws_size,
                              hipStream_t stream) {
    (void)in_sizes; (void)n_in; (void)out_size; (void)ws_size;
    const float* z   = (const float*)d_in[0];
    const float* emb = (const float*)d_in[1];
    float* out = (float*)d_out;
    char* ws = (char*)d_ws;
    unsigned short* embB = (unsigned short*)(ws + EMBB_OFF);
    float* enorm   = (float*)(ws + ENORM_OFF);
    int*   hist    = (int*)(ws + HIST_OFF);
    float* lossAcc = (float*)(ws + LOSS_OFF);
    int*   gcnt    = (int*)(ws + GCNT_OFF);
    int*   gdone   = (int*)(ws + GDONE_OFF);
    unsigned long long* best64 = (unsigned long long*)(ws + BEST_OFF);

    prep_emb<<<64, 256, 0, stream>>>(emb, embB, enorm, hist, lossAcc,
                                     gcnt, gdone, best64);
    fused_kernel<<<1024, 256, 0, stream>>>(z, emb, embB, enorm, out, hist,
                                           lossAcc, gcnt, gdone, best64, out);
}

// Round 11
// 158.074 us; speedup vs baseline: 1.0792x; 1.0792x over previous
//
#include <hip/hip_runtime.h>
#include <cfloat>

typedef __attribute__((ext_vector_type(8))) short short8;
typedef __attribute__((ext_vector_type(4))) float f32x4;

#define NE 1024
#define EDIM 256
#define HW 1024
#define BSTRIDE (EDIM * HW)        // 262144
#define TOTAL 8388608

// workspace layout (bytes)
#define EMBB_OFF  0                        // ushort[1024*256] bf16 = 512 KB
#define ENORM_OFF (512 * 1024)             // float[1024]
#define HIST_OFF  (ENORM_OFF + 4096)       // int[1024]
#define LOSS_OFF  (HIST_OFF + 4096)        // float[64] banked loss accum
#define GCNT_OFF  (LOSS_OFF + 256)         // int[512] per-group twin counter
#define GDONE_OFF (GCNT_OFF + 2048)        // int completion counter
#define BEST_OFF  (GDONE_OFF + 16)         // u64[32768] packed (dist,code)

// round-to-nearest-even fp32 -> bf16 bits (inputs are finite)
__device__ __forceinline__ unsigned short f2bf(float x) {
    unsigned u = __builtin_bit_cast(unsigned, x);
    return (unsigned short)((u + 0x7fffu + ((u >> 16) & 1u)) >> 16);
}

// async global->LDS, 16B per lane, LDS dest = uniform base + lane*16
__device__ __forceinline__ void stage16(const void* g, void* l) {
    __builtin_amdgcn_global_load_lds(
        (const __attribute__((address_space(1))) unsigned int*)g,
        (__attribute__((address_space(3))) unsigned int*)l, 16, 0, 0);
}

// ---------------------------------------------------------------------------
// P: emb fp32 [1024][256] -> embB bf16 rows + enorm. 64 blocks x 256 thr.
// Also inits best64 (all blocks) and hist/loss/gcnt/gdone (block 0).
// ---------------------------------------------------------------------------
__global__ void prep_emb(const float* __restrict__ emb,
                         unsigned short* __restrict__ embB,
                         float* __restrict__ enorm,
                         int* __restrict__ hist,
                         float* __restrict__ lossAcc,
                         int* __restrict__ gcnt,
                         int* __restrict__ gdone,
                         unsigned long long* __restrict__ best64) {
    int t = threadIdx.x;
    int gid = blockIdx.x * 256 + t;        // 0..16383
    int row = gid >> 4, seg = gid & 15;
    const float4* e4 = (const float4*)(emb + (size_t)row * EDIM) + seg * 4;
    float4 a0 = e4[0], a1 = e4[1], a2 = e4[2], a3 = e4[3];
    float s = a0.x * a0.x + a0.y * a0.y + a0.z * a0.z + a0.w * a0.w
            + a1.x * a1.x + a1.y * a1.y + a1.z * a1.z + a1.w * a1.w
            + a2.x * a2.x + a2.y * a2.y + a2.z * a2.z + a2.w * a2.w
            + a3.x * a3.x + a3.y * a3.y + a3.z * a3.z + a3.w * a3.w;
    short8 v0, v1;
    v0[0] = (short)f2bf(a0.x); v0[1] = (short)f2bf(a0.y);
    v0[2] = (short)f2bf(a0.z); v0[3] = (short)f2bf(a0.w);
    v0[4] = (short)f2bf(a1.x); v0[5] = (short)f2bf(a1.y);
    v0[6] = (short)f2bf(a1.z); v0[7] = (short)f2bf(a1.w);
    v1[0] = (short)f2bf(a2.x); v1[1] = (short)f2bf(a2.y);
    v1[2] = (short)f2bf(a2.z); v1[3] = (short)f2bf(a2.w);
    v1[4] = (short)f2bf(a3.x); v1[5] = (short)f2bf(a3.y);
    v1[6] = (short)f2bf(a3.z); v1[7] = (short)f2bf(a3.w);
    *(short8*)&embB[(size_t)row * EDIM + seg * 16]     = v0;
    *(short8*)&embB[(size_t)row * EDIM + seg * 16 + 8] = v1;
    s += __shfl_xor(s, 1, 64);
    s += __shfl_xor(s, 2, 64);
    s += __shfl_xor(s, 4, 64);
    s += __shfl_xor(s, 8, 64);
    if (seg == 0) enorm[row] = s;
    size_t b0 = (size_t)blockIdx.x * 512 + (size_t)t * 2;
    best64[b0] = ~0ULL; best64[b0 + 1] = ~0ULL;
    if (blockIdx.x == 0) {
        ((int4*)hist)[t] = (int4){0, 0, 0, 0};
        if (t < 64)  lossAcc[t] = 0.f;
        if (t < 128) ((int4*)gcnt)[t] = (int4){0, 0, 0, 0};
        if (t == 0)  gdone[0] = 0;
    }
}

// ---------------------------------------------------------------------------
// F: fused argmin GEMM (M=32768,N=1024,K=256) + gather + loss + hist.
// R10 body, UNCHANGED, with the single isolated variable flipped:
// __launch_bounds__(256, 3).
//   - (,2) rounds (R0,R2,R5,R6,R7,R9): healthy regalloc (88-128 VGPR, no
//     spill) but occupancy pinned 19-25% -> best fused 87us.
//   - (,4) rounds (R1,R3,R4,R10): regalloc ALWAYS collapses to 48-64 VGPR
//     + scratch (R10: WRITE 34->67MB spill, first dispatch 193us scratch
//     init) -- yet R10 still hit 100us at 30% occupancy. Occupancy works;
//     (,4) codegen is broken for this loop.
//   - (,3): VGPR cap 512/3 = 168 >> ~130 live set -> no spill; 3 blocks/CU
//     = 12 waves/CU = 37.5% occupancy cap > R10's achieved 30%.
// Everything else proven in R10 (passed): global_load_lds B staging (zero
// register footprint, XOR-swizzled source + swizzled ds_read, rule 21),
// one barrier per tile, XCD twin pairing (FETCH 22.7MB, R9), loss from
// ||z||^2 + unpacked d_min (no owner z re-read).
// ---------------------------------------------------------------------------
__global__ __launch_bounds__(256, 3) void fused_kernel(
        const float* __restrict__ z, const float* __restrict__ emb,
        const unsigned short* __restrict__ embB, const float* __restrict__ enormG,
        float* __restrict__ zq, int* __restrict__ hist,
        float* __restrict__ lossAcc, int* __restrict__ gcnt,
        int* __restrict__ gdone, unsigned long long* __restrict__ best64,
        float* __restrict__ out) {
    // union: As 64x264 bf16 (33792 B) during A-stage; then 2 B buffers
    // of 32 codes x 512 B (2 x 16384 B) inside the same region.
    __shared__ __align__(16) unsigned char uni[33792];
    __shared__ float Ens[512];
    __shared__ float znp[4][64];
    __shared__ float zn[64];
    __shared__ float rv[2][64];
    __shared__ int   ri[2][64];
    __shared__ int   idxm[64];
    __shared__ int   amOwner, amLast;
    __shared__ float wsum[4];

    unsigned short* As = (unsigned short*)uni;

    int t = threadIdx.x;                   // 0..255
    int bid = blockIdx.x;
    int h = (bid >> 3) & 1;                // code half; twins differ by +8 -> same XCD
    int g = (bid & 7) | ((bid >> 4) << 3); // position group 0..511 (bijective)
    int m0 = g * 64;
    int b = m0 >> 10, pb = m0 & 1023;
    const float* zb  = z  + (size_t)b * BSTRIDE + pb;
    float*       zqb = zq + (size_t)b * BSTRIDE + pb;

    for (int j = t; j < 512; j += 256) Ens[j] = enormG[h * 512 + j];

    int pq = t & 15, cg = t >> 4;          // p-quad 0..15, 16-ch group 0..15
    float s0 = 0.f, s1 = 0.f, s2 = 0.f, s3 = 0.f;   // ||z||^2 partials per pos
    {   // stage A: 64 pos x 256 ch, float4 loads along p, short8 LDS writes
        const float* zp = zb + pq * 4;
#pragma unroll
        for (int hh = 0; hh < 2; ++hh) {
            float4 zv[8];
#pragma unroll
            for (int v = 0; v < 8; ++v)
                zv[v] = *(const float4*)&zp[(size_t)(cg * 16 + hh * 8 + v) * HW];
#pragma unroll
            for (int v = 0; v < 8; ++v) {
                s0 += zv[v].x * zv[v].x; s1 += zv[v].y * zv[v].y;
                s2 += zv[v].z * zv[v].z; s3 += zv[v].w * zv[v].w;
            }
#pragma unroll
            for (int j = 0; j < 4; ++j) {
                short8 w8;
#pragma unroll
                for (int v = 0; v < 8; ++v) {
                    float x = (j == 0) ? zv[v].x : (j == 1) ? zv[v].y
                            : (j == 2) ? zv[v].z : zv[v].w;
                    w8[v] = (short)f2bf(x);
                }
                *(short8*)&As[(pq * 4 + j) * 264 + cg * 16 + hh * 8] = w8;
            }
        }
    }
    int w = t >> 6, l = t & 63, lm = l & 15, q = l >> 4;
    // reduce ||z||^2 partials across the wave's 4 channel-groups
    s0 += __shfl_xor(s0, 16, 64); s0 += __shfl_xor(s0, 32, 64);
    s1 += __shfl_xor(s1, 16, 64); s1 += __shfl_xor(s1, 32, 64);
    s2 += __shfl_xor(s2, 16, 64); s2 += __shfl_xor(s2, 32, 64);
    s3 += __shfl_xor(s3, 16, 64); s3 += __shfl_xor(s3, 32, 64);
    if (l < 16) {
        znp[w][pq * 4 + 0] = s0; znp[w][pq * 4 + 1] = s1;
        znp[w][pq * 4 + 2] = s2; znp[w][pq * 4 + 3] = s3;
    }
    __syncthreads();                       // B1: As + znp complete

    int mw = w >> 1, nw = w & 1;           // mw: 32-pos half, nw: 32-code half

    short8 A[2][8];                        // all 64 pos (2 m-frags x 8 k-slices)
#pragma unroll
    for (int s = 0; s < 2; ++s)
#pragma unroll
        for (int ks = 0; ks < 8; ++ks)
            A[s][ks] = *(const short8*)&As[(mw * 32 + s * 16 + lm) * 264 + ks * 32 + q * 8];

    float bd[8]; int bi[8];
#pragma unroll
    for (int i = 0; i < 8; ++i) { bd[i] = FLT_MAX; bi[i] = 0x7fffffff; }

    __syncthreads();                       // B2: As dead; uni becomes B dbuf
    if (t < 64) zn[t] = znp[0][t] + znp[1][t] + znp[2][t] + znp[3][t];

    // --- staging address precompute (per lane) ---
    // tile = 32 rows x 512 B; wave w covers rows [w*8, w*8+8) via 4 issues
    // of 2 rows (1 KB) each. lane l writes phys byte l*16 of the window:
    // row = w*8+2i+(l>>5), pb = (l&31)*16; source logical o = pb ^ ((row&7)<<4).
    const char* eBb = (const char*)embB + (size_t)(h * 512) * 512;
    int rIn = l >> 5, poB = (l & 31) << 4;
    int sOff0 = (w * 8 + 0 + rIn) * 512 + (poB ^ (((0 + rIn) & 7) << 4));
    int sOff1 = (w * 8 + 2 + rIn) * 512 + (poB ^ (((2 + rIn) & 7) << 4));
    int sOff2 = (w * 8 + 4 + rIn) * 512 + (poB ^ (((4 + rIn) & 7) << 4));
    int sOff3 = (w * 8 + 6 + rIn) * 512 + (poB ^ (((6 + rIn) & 7) << 4));
    int lB0 = (w * 8 + 0) * 512, lB1 = (w * 8 + 2) * 512;
    int lB2 = (w * 8 + 4) * 512, lB3 = (w * 8 + 6) * 512;

    {   // stage tile 0 -> buf0
        const char* gs = eBb;
        stage16(gs + sOff0, uni + lB0); stage16(gs + sOff1, uni + lB1);
        stage16(gs + sOff2, uni + lB2); stage16(gs + sOff3, uni + lB3);
    }

    // --- swizzled ds_read bases: logical o = ks*64 + q*16 at row cl ->
    // phys = cl*512 + (o ^ ((cl&7)<<4)); split even/odd ks (bit6) ---
    int cl = nw * 16 + lm;
    int baseE = cl * 512 + ((q << 4) ^ ((cl & 3) << 4)) + ((cl & 4) << 4);
    int baseO = baseE ^ 64;

#pragma unroll 2
    for (int nt = 0; nt < 16; ++nt) {
        __syncthreads();                   // drains stage(nt); buf ready
        if (nt < 15) {                     // stage nt+1 into the idle buffer
            const char* gs = eBb + (size_t)(nt + 1) * 32 * 512;
            char* lb = (char*)uni + (size_t)((nt + 1) & 1) * 16384;
            stage16(gs + sOff0, lb + lB0); stage16(gs + sOff1, lb + lB1);
            stage16(gs + sOff2, lb + lB2); stage16(gs + sOff3, lb + lB3);
        }
        const char* Bc = (const char*)uni + (size_t)(nt & 1) * 16384;
        f32x4 a0a = {0,0,0,0}, a0b = {0,0,0,0};
        f32x4 a1a = {0,0,0,0}, a1b = {0,0,0,0};
#pragma unroll
        for (int ks = 0; ks < 8; ks += 2) {
            short8 Bv0 = *(const short8*)(Bc + baseE + (ks >> 1) * 128);
            short8 Bv1 = *(const short8*)(Bc + baseO + (ks >> 1) * 128);
            a0a = __builtin_amdgcn_mfma_f32_16x16x32_bf16(A[0][ks],     Bv0, a0a, 0, 0, 0);
            a1a = __builtin_amdgcn_mfma_f32_16x16x32_bf16(A[1][ks],     Bv0, a1a, 0, 0, 0);
            a0b = __builtin_amdgcn_mfma_f32_16x16x32_bf16(A[0][ks + 1], Bv1, a0b, 0, 0, 0);
            a1b = __builtin_amdgcn_mfma_f32_16x16x32_bf16(A[1][ks + 1], Bv1, a1b, 0, 0, 0);
        }
        float en = Ens[nt * 32 + cl];
        int code = h * 512 + nt * 32 + cl;
#pragma unroll
        for (int r = 0; r < 4; ++r) {
            float d0 = en - 2.f * (a0a[r] + a0b[r]);
            if (d0 < bd[r])     { bd[r] = d0;     bi[r] = code; }
            float d1 = en - 2.f * (a1a[r] + a1b[r]);
            if (d1 < bd[4 + r]) { bd[4 + r] = d1; bi[4 + r] = code; }
        }
    }

    // reduce across the 16 code-columns (lanes sharing q)
#pragma unroll
    for (int off = 1; off < 16; off <<= 1) {
#pragma unroll
        for (int i = 0; i < 8; ++i) {
            float od = __shfl_xor(bd[i], off, 64);
            int   oi = __shfl_xor(bi[i], off, 64);
            if (od < bd[i] || (od == bd[i] && oi < bi[i])) { bd[i] = od; bi[i] = oi; }
        }
    }
    if (lm == 0) {
#pragma unroll
        for (int s = 0; s < 2; ++s)
#pragma unroll
            for (int r = 0; r < 4; ++r) {
                int p = mw * 32 + s * 16 + q * 4 + r;
                rv[nw][p] = bd[s * 4 + r];
                ri[nw][p] = bi[s * 4 + r];
            }
    }
    __syncthreads();
    if (t < 64) {   // merge nw halves, publish to global packed argmin
        float v0 = rv[0][t]; int i0 = ri[0][t];
        float v1 = rv[1][t]; int i1 = ri[1][t];
        float v = (v1 < v0 || (v1 == v0 && i1 < i0)) ? v1 : v0;
        int bix  = (v1 < v0 || (v1 == v0 && i1 < i0)) ? i1 : i0;
        unsigned ub = __builtin_bit_cast(unsigned, v);
        ub = (ub & 0x80000000u) ? ~ub : (ub | 0x80000000u);   // order-preserving
        unsigned long long pk = ((unsigned long long)ub << 32) | (unsigned)bix;
        atomicMin(&best64[(size_t)g * 64 + t], pk);
    }
    __syncthreads();
    if (t == 0) {
        __threadfence();
        amOwner = (atomicAdd(&gcnt[g], 1) == 1);   // 2nd finisher owns epilogue
    }
    __syncthreads();
    if (!amOwner) return;

    if (t < 64) {   // winners: code + exact d (unmap), hist + loss in one pass
        unsigned long long pk = atomicAdd(&best64[(size_t)g * 64 + t], 0ULL);
        int code = (int)(pk & 0xFFFFFFFFull);
        unsigned ub = (unsigned)(pk >> 32);
        unsigned du = (ub & 0x80000000u) ? (ub & 0x7FFFFFFFu) : ~ub;   // inverse map
        float d = __builtin_bit_cast(float, du);
        idxm[t] = code;
        atomicAdd(&hist[code], 1);
        float ls = zn[t] + d;              // sum over channels of (z-e)^2
        ls += __shfl_down(ls, 32, 64); ls += __shfl_down(ls, 16, 64);
        ls += __shfl_down(ls, 8, 64);  ls += __shfl_down(ls, 4, 64);
        ls += __shfl_down(ls, 2, 64);  ls += __shfl_down(ls, 1, 64);
        if (t == 0) atomicAdd(&lossAcc[g & 63], ls);
    }
    __syncthreads();

    {   // epilogue: gather 4 emb rows x 16 ch, write z_q (no z re-read)
        int p0 = pq * 4;
        int k0 = idxm[p0], k1 = idxm[p0 + 1], k2 = idxm[p0 + 2], k3 = idxm[p0 + 3];
#pragma unroll
        for (int hh = 0; hh < 2; ++hh) {
            int cb = cg * 16 + hh * 8;
            float e0[8], e1[8], e2[8], e3[8];
            {
                const float4* a = (const float4*)(emb + (size_t)k0 * EDIM) + (cb >> 2);
                *(float4*)&e0[0] = a[0]; *(float4*)&e0[4] = a[1];
            }
            {
                const float4* a = (const float4*)(emb + (size_t)k1 * EDIM) + (cb >> 2);
                *(float4*)&e1[0] = a[0]; *(float4*)&e1[4] = a[1];
            }
            {
                const float4* a = (const float4*)(emb + (size_t)k2 * EDIM) + (cb >> 2);
                *(float4*)&e2[0] = a[0]; *(float4*)&e2[4] = a[1];
            }
            {
                const float4* a = (const float4*)(emb + (size_t)k3 * EDIM) + (cb >> 2);
                *(float4*)&e3[0] = a[0]; *(float4*)&e3[4] = a[1];
            }
#pragma unroll
            for (int v = 0; v < 8; ++v) {
                float4 qv; qv.x = e0[v]; qv.y = e1[v]; qv.z = e2[v]; qv.w = e3[v];
                *(float4*)&zqb[(size_t)(cb + v) * HW + p0] = qv;
            }
        }
    }

    // last-owner finalize
    if (t == 0) {
        __threadfence();
        amLast = (atomicAdd(gdone, 1) == 511);
    }
    __syncthreads();
    if (amLast) {
        float s = 0.f;
        for (int j = t; j < NE; j += 256) {
            float p = (float)atomicAdd(&hist[j], 0) * (1.0f / 32768.0f);
            s += p * logf(p + 1e-10f);
        }
#pragma unroll
        for (int off = 32; off; off >>= 1) s += __shfl_down(s, off, 64);
        if ((t & 63) == 0) wsum[t >> 6] = s;
        float lt = 0.f;
        if (t < 64) lt = atomicAdd(&lossAcc[t], 0.f);
#pragma unroll
        for (int off = 32; off; off >>= 1) lt += __shfl_down(lt, off, 64);
        __syncthreads();
        if (t == 0) {
            float S = wsum[0] + wsum[1] + wsum[2] + wsum[3];
            out[TOTAL]     = 1.25f * lt / (float)TOTAL;
            out[TOTAL + 1] = expf(-S);
        }
    }
}

extern "C" void kernel_launch(void* const* d_in, const int* in_sizes, int n_in,
                              void* d_out, int out_size, void* d_ws, size_t ws_size,
                              hipStream_t stream) {
    (void)in_sizes; (void)n_in; (void)out_size; (void)ws_size;
    const float* z   = (const float*)d_in[0];
    const float* emb = (const float*)d_in[1];
    float* out = (float*)d_out;
    char* ws = (char*)d_ws;
    unsigned short* embB = (unsigned short*)(ws + EMBB_OFF);
    float* enorm   = (float*)(ws + ENORM_OFF);
    int*   hist    = (int*)(ws + HIST_OFF);
    float* lossAcc = (float*)(ws + LOSS_OFF);
    int*   gcnt    = (int*)(ws + GCNT_OFF);
    int*   gdone   = (int*)(ws + GDONE_OFF);
    unsigned long long* best64 = (unsigned long long*)(ws + BEST_OFF);

    prep_emb<<<64, 256, 0, stream>>>(emb, embB, enorm, hist, lossAcc,
                                     gcnt, gdone, best64);
    fused_kernel<<<1024, 256, 0, stream>>>(z, emb, embB, enorm, out, hist,
                                           lossAcc, gcnt, gdone, best64, out);
}

// Round 13
// 135.024 us; speedup vs baseline: 1.2634x; 1.1707x over previous
//
#include <hip/hip_runtime.h>
#include <cfloat>

typedef __attribute__((ext_vector_type(8))) short short8;
typedef __attribute__((ext_vector_type(4))) float f32x4;

#define NE 1024
#define EDIM 256
#define HW 1024
#define BSTRIDE (EDIM * HW)        // 262144
#define TOTAL 8388608

// workspace layout (bytes)
#define EMBB_OFF  0                        // ushort[1024*256] bf16 = 512 KB
#define ENORM_OFF (512 * 1024)             // float[1024]
#define HIST_OFF  (ENORM_OFF + 4096)       // int[1024]
#define LOSS_OFF  (HIST_OFF + 4096)       // float[64] banked loss accum
#define GDONE_OFF (LOSS_OFF + 256)         // int completion counter

// round-to-nearest-even fp32 -> bf16 bits (inputs are finite)
__device__ __forceinline__ unsigned short f2bf(float x) {
    unsigned u = __builtin_bit_cast(unsigned, x);
    return (unsigned short)((u + 0x7fffu + ((u >> 16) & 1u)) >> 16);
}

// ---------------------------------------------------------------------------
// P: emb fp32 [1024][256] -> embB bf16 rows + enorm. 64 blocks x 256 thr.
// Block 0 also zeroes hist/loss/gdone. (No best64/gcnt: block-local argmin
// this round — R12's cooperative single-dispatch failed because
// hipLaunchCooperativeKernel is not graph-capturable in this harness.)
// ---------------------------------------------------------------------------
__global__ void prep_emb(const float* __restrict__ emb,
                         unsigned short* __restrict__ embB,
                         float* __restrict__ enorm,
                         int* __restrict__ hist,
                         float* __restrict__ lossAcc,
                         int* __restrict__ gdone) {
    int t = threadIdx.x;
    int gid = blockIdx.x * 256 + t;        // 0..16383
    int row = gid >> 4, seg = gid & 15;
    const float4* e4 = (const float4*)(emb + (size_t)row * EDIM) + seg * 4;
    float4 a0 = e4[0], a1 = e4[1], a2 = e4[2], a3 = e4[3];
    float s = a0.x * a0.x + a0.y * a0.y + a0.z * a0.z + a0.w * a0.w
            + a1.x * a1.x + a1.y * a1.y + a1.z * a1.z + a1.w * a1.w
            + a2.x * a2.x + a2.y * a2.y + a2.z * a2.z + a2.w * a2.w
            + a3.x * a3.x + a3.y * a3.y + a3.z * a3.z + a3.w * a3.w;
    short8 v0, v1;
    v0[0] = (short)f2bf(a0.x); v0[1] = (short)f2bf(a0.y);
    v0[2] = (short)f2bf(a0.z); v0[3] = (short)f2bf(a0.w);
    v0[4] = (short)f2bf(a1.x); v0[5] = (short)f2bf(a1.y);
    v0[6] = (short)f2bf(a1.z); v0[7] = (short)f2bf(a1.w);
    v1[0] = (short)f2bf(a2.x); v1[1] = (short)f2bf(a2.y);
    v1[2] = (short)f2bf(a2.z); v1[3] = (short)f2bf(a2.w);
    v1[4] = (short)f2bf(a3.x); v1[5] = (short)f2bf(a3.y);
    v1[6] = (short)f2bf(a3.z); v1[7] = (short)f2bf(a3.w);
    *(short8*)&embB[(size_t)row * EDIM + seg * 16]     = v0;
    *(short8*)&embB[(size_t)row * EDIM + seg * 16 + 8] = v1;
    s += __shfl_xor(s, 1, 64);
    s += __shfl_xor(s, 2, 64);
    s += __shfl_xor(s, 4, 64);
    s += __shfl_xor(s, 8, 64);
    if (seg == 0) enorm[row] = s;
    if (blockIdx.x == 0) {
        ((int4*)hist)[t] = (int4){0, 0, 0, 0};
        if (t < 64) lossAcc[t] = 0.f;
        if (t == 0) gdone[0] = 0;
    }
}

// ---------------------------------------------------------------------------
// F: fused argmin GEMM + gather + loss + hist + folded finalize.
// The leanest member of the proven family: R6's 16-tile reg-prefetch loop
// (2 barriers/tile, 64-pos block, grid 512, all 1024 codes per block ->
// block-local argmin, NO cross-block merge machinery) combined with the
// R10/R11-proven subtractions R6 lacked:
//  - loss = sum(||z||^2) + d_min: zn computed exactly in fp32 during the
//    A-stage, d_min is the argmin value itself -> R6's epilogue z re-read
//    (~33MB round-trips + a latency phase) deleted;
//  - direct-gather epilogue (no Es transpose buffer, one less barrier);
//  - folded gdone finalize (proven R3-R11).
// launch_bounds(256,2): the only setting with healthy regalloc for this
// loop (the (,3)/(,4) story is settled: (,4) collapses to 64 VGPR + spill,
// (,3) didn't raise achieved occupancy). Occupancy ~19% is the accepted
// structural cap; the fused work-phase is at the small-N GEMM-ladder
// ceiling (~190TF on 17.2 GFLOP); this round only removes epilogue work.
// ---------------------------------------------------------------------------
__global__ __launch_bounds__(256, 2) void vq_main(
        const float* __restrict__ z, const float* __restrict__ emb,
        const unsigned short* __restrict__ embB, const float* __restrict__ enormG,
        float* __restrict__ zq, int* __restrict__ hist,
        float* __restrict__ lossAcc, int* __restrict__ gdone,
        float* __restrict__ out) {
    __shared__ __align__(16) unsigned short As[64 * 264];   // 33.8 KB
    __shared__ __align__(16) unsigned short Bs[64 * 264];   // 33.8 KB
    __shared__ float Ens[NE];
    __shared__ float znp[4][64];
    __shared__ float zn[64];
    __shared__ float rv[2][64];
    __shared__ int   ri[2][64];
    __shared__ int   idxm[64];
    __shared__ int   amLast;
    __shared__ float wsum[4];

    int t = threadIdx.x;                   // 0..255
    int bid = blockIdx.x;                  // 0..511
    int m0 = bid * 64;
    int b = m0 >> 10, pb = m0 & 1023;
    const float* zb  = z  + (size_t)b * BSTRIDE + pb;
    float*       zqb = zq + (size_t)b * BSTRIDE + pb;

    for (int j = t; j < NE; j += 256) Ens[j] = enormG[j];

    int pq = t & 15, cg = t >> 4;          // p-quad 0..15, 16-ch group 0..15
    float s0 = 0.f, s1 = 0.f, s2 = 0.f, s3 = 0.f;   // ||z||^2 partials
    {   // A-stage: 64 pos x 256 ch, float4 loads along p, short8 LDS writes
        const float* zp = zb + pq * 4;
#pragma unroll
        for (int hh = 0; hh < 2; ++hh) {
            float4 zv[8];
#pragma unroll
            for (int v = 0; v < 8; ++v)
                zv[v] = *(const float4*)&zp[(size_t)(cg * 16 + hh * 8 + v) * HW];
#pragma unroll
            for (int v = 0; v < 8; ++v) {
                s0 += zv[v].x * zv[v].x; s1 += zv[v].y * zv[v].y;
                s2 += zv[v].z * zv[v].z; s3 += zv[v].w * zv[v].w;
            }
#pragma unroll
            for (int j = 0; j < 4; ++j) {
                short8 w8;
#pragma unroll
                for (int v = 0; v < 8; ++v) {
                    float x = (j == 0) ? zv[v].x : (j == 1) ? zv[v].y
                            : (j == 2) ? zv[v].z : zv[v].w;
                    w8[v] = (short)f2bf(x);
                }
                *(short8*)&As[(pq * 4 + j) * 264 + cg * 16 + hh * 8] = w8;
            }
        }
    }

    int w = t >> 6, l = t & 63, lm = l & 15, q = l >> 4;
    // reduce ||z||^2 partials across the wave's 4 channel-groups
    s0 += __shfl_xor(s0, 16, 64); s0 += __shfl_xor(s0, 32, 64);
    s1 += __shfl_xor(s1, 16, 64); s1 += __shfl_xor(s1, 32, 64);
    s2 += __shfl_xor(s2, 16, 64); s2 += __shfl_xor(s2, 32, 64);
    s3 += __shfl_xor(s3, 16, 64); s3 += __shfl_xor(s3, 32, 64);
    if (l < 16) {
        znp[w][pq * 4 + 0] = s0; znp[w][pq * 4 + 1] = s1;
        znp[w][pq * 4 + 2] = s2; znp[w][pq * 4 + 3] = s3;
    }

    // tile-0 B prefetch (flies under the A-frag ds_reads)
    const short8* eB8 = (const short8*)embB;
    short8 pref[8];
#pragma unroll
    for (int i = 0; i < 8; ++i) {
        int slot = i * 256 + t;
        pref[i] = eB8[(size_t)(slot >> 5) * 32 + (slot & 31)];
    }
    __syncthreads();                       // As + znp complete

    int mw = w >> 1, nw = w & 1;           // mw: 32-pos half, nw: 32-code half

    short8 A[2][8];                        // all 64 pos (2 m-frags x 8 k-slices)
#pragma unroll
    for (int s = 0; s < 2; ++s)
#pragma unroll
        for (int ks = 0; ks < 8; ++ks)
            A[s][ks] = *(const short8*)&As[(mw * 32 + s * 16 + lm) * 264 + ks * 32 + q * 8];

    float bd[8]; int bi[8];
#pragma unroll
    for (int i = 0; i < 8; ++i) { bd[i] = FLT_MAX; bi[i] = 0x7fffffff; }

    if (t < 64) zn[t] = znp[0][t] + znp[1][t] + znp[2][t] + znp[3][t];

    {   // write tile 0 into Bs
        short8* Bw = (short8*)Bs;
#pragma unroll
        for (int i = 0; i < 8; ++i) {
            int slot = i * 256 + t;
            Bw[(slot >> 5) * 33 + (slot & 31)] = pref[i];
        }
    }

#pragma unroll 2
    for (int nt = 0; nt < 16; ++nt) {
        __syncthreads();                   // tile nt writes visible
        if (nt < 15) {                     // prefetch next tile -> regs
            int n1 = (nt + 1) * 64;
#pragma unroll
            for (int i = 0; i < 8; ++i) {
                int slot = i * 256 + t;
                pref[i] = eB8[(size_t)(n1 + (slot >> 5)) * 32 + (slot & 31)];
            }
        }
        int n0 = nt * 64;
#pragma unroll
        for (int nf = 0; nf < 2; ++nf) {
            int cl = nw * 32 + nf * 16 + lm;
            float en = Ens[n0 + cl];
            f32x4 a0a = {0,0,0,0}, a0b = {0,0,0,0};
            f32x4 a1a = {0,0,0,0}, a1b = {0,0,0,0};
#pragma unroll
            for (int ks = 0; ks < 8; ks += 2) {
                short8 Bv0 = *(const short8*)&Bs[cl * 264 + ks * 32 + q * 8];
                short8 Bv1 = *(const short8*)&Bs[cl * 264 + (ks + 1) * 32 + q * 8];
                a0a = __builtin_amdgcn_mfma_f32_16x16x32_bf16(A[0][ks],     Bv0, a0a, 0, 0, 0);
                a1a = __builtin_amdgcn_mfma_f32_16x16x32_bf16(A[1][ks],     Bv0, a1a, 0, 0, 0);
                a0b = __builtin_amdgcn_mfma_f32_16x16x32_bf16(A[0][ks + 1], Bv1, a0b, 0, 0, 0);
                a1b = __builtin_amdgcn_mfma_f32_16x16x32_bf16(A[1][ks + 1], Bv1, a1b, 0, 0, 0);
            }
            int code = n0 + cl;
#pragma unroll
            for (int r = 0; r < 4; ++r) {
                float d0 = en - 2.f * (a0a[r] + a0b[r]);
                if (d0 < bd[r])     { bd[r] = d0;     bi[r] = code; }
                float d1 = en - 2.f * (a1a[r] + a1b[r]);
                if (d1 < bd[4 + r]) { bd[4 + r] = d1; bi[4 + r] = code; }
            }
        }
        __syncthreads();                   // tile nt consumed
        if (nt < 15) {                     // drain prefetch into Bs
            short8* Bw = (short8*)Bs;
#pragma unroll
            for (int i = 0; i < 8; ++i) {
                int slot = i * 256 + t;
                Bw[(slot >> 5) * 33 + (slot & 31)] = pref[i];
            }
        }
    }

    // reduce across the 16 code-columns (lanes sharing q)
#pragma unroll
    for (int off = 1; off < 16; off <<= 1) {
#pragma unroll
        for (int i = 0; i < 8; ++i) {
            float od = __shfl_xor(bd[i], off, 64);
            int   oi = __shfl_xor(bi[i], off, 64);
            if (od < bd[i] || (od == bd[i] && oi < bi[i])) { bd[i] = od; bi[i] = oi; }
        }
    }
    if (lm == 0) {
#pragma unroll
        for (int s = 0; s < 2; ++s)
#pragma unroll
            for (int r = 0; r < 4; ++r) {
                int p = mw * 32 + s * 16 + q * 4 + r;
                rv[nw][p] = bd[s * 4 + r];
                ri[nw][p] = bi[s * 4 + r];
            }
    }
    __syncthreads();
    if (t < 64) {   // block-local merge of the 2 code halves; hist + loss
        float v0 = rv[0][t]; int i0 = ri[0][t];
        float v1 = rv[1][t]; int i1 = ri[1][t];
        float v = (v1 < v0 || (v1 == v0 && i1 < i0)) ? v1 : v0;
        int bix  = (v1 < v0 || (v1 == v0 && i1 < i0)) ? i1 : i0;
        idxm[t] = bix;
        atomicAdd(&hist[bix], 1);
        float ls = zn[t] + v;              // sum over channels of (z-e)^2
        ls += __shfl_down(ls, 32, 64); ls += __shfl_down(ls, 16, 64);
        ls += __shfl_down(ls, 8, 64);  ls += __shfl_down(ls, 4, 64);
        ls += __shfl_down(ls, 2, 64);  ls += __shfl_down(ls, 1, 64);
        if (t == 0) atomicAdd(&lossAcc[bid & 63], ls);
    }
    __syncthreads();

    {   // epilogue: gather 4 emb rows x 16 ch, write z_q (no z re-read)
        int p0 = pq * 4;
        int k0 = idxm[p0], k1 = idxm[p0 + 1], k2 = idxm[p0 + 2], k3 = idxm[p0 + 3];
#pragma unroll
        for (int hh = 0; hh < 2; ++hh) {
            int cb = cg * 16 + hh * 8;
            float e0[8], e1[8], e2[8], e3[8];
            {
                const float4* a = (const float4*)(emb + (size_t)k0 * EDIM) + (cb >> 2);
                *(float4*)&e0[0] = a[0]; *(float4*)&e0[4] = a[1];
            }
            {
                const float4* a = (const float4*)(emb + (size_t)k1 * EDIM) + (cb >> 2);
                *(float4*)&e1[0] = a[0]; *(float4*)&e1[4] = a[1];
            }
            {
                const float4* a = (const float4*)(emb + (size_t)k2 * EDIM) + (cb >> 2);
                *(float4*)&e2[0] = a[0]; *(float4*)&e2[4] = a[1];
            }
            {
                const float4* a = (const float4*)(emb + (size_t)k3 * EDIM) + (cb >> 2);
                *(float4*)&e3[0] = a[0]; *(float4*)&e3[4] = a[1];
            }
#pragma unroll
            for (int v = 0; v < 8; ++v) {
                float4 qv; qv.x = e0[v]; qv.y = e1[v]; qv.z = e2[v]; qv.w = e3[v];
                *(float4*)&zqb[(size_t)(cb + v) * HW + p0] = qv;
            }
        }
    }

    // last-block finalize
    if (t == 0) {
        __threadfence();
        amLast = (atomicAdd(gdone, 1) == (int)gridDim.x - 1);
    }
    __syncthreads();
    if (amLast) {
        float s = 0.f;
        for (int j = t; j < NE; j += 256) {
            float p = (float)atomicAdd(&hist[j], 0) * (1.0f / 32768.0f);
            s += p * logf(p + 1e-10f);
        }
#pragma unroll
        for (int off = 32; off; off >>= 1) s += __shfl_down(s, off, 64);
        if ((t & 63) == 0) wsum[t >> 6] = s;
        float lt = 0.f;
        if (t < 64) lt = atomicAdd(&lossAcc[t], 0.f);
#pragma unroll
        for (int off = 32; off; off >>= 1) lt += __shfl_down(lt, off, 64);
        __syncthreads();
        if (t == 0) {
            float S = wsum[0] + wsum[1] + wsum[2] + wsum[3];
            out[TOTAL]     = 1.25f * lt / (float)TOTAL;
            out[TOTAL + 1] = expf(-S);
        }
    }
}

extern "C" void kernel_launch(void* const* d_in, const int* in_sizes, int n_in,
                              void* d_out, int out_size, void* d_ws, size_t ws_size,
                              hipStream_t stream) {
    (void)in_sizes; (void)n_in; (void)out_size; (void)ws_size;
    const float* z   = (const float*)d_in[0];
    const float* emb = (const float*)d_in[1];
    float* out = (float*)d_out;
    char* ws = (char*)d_ws;
    unsigned short* embB = (unsigned short*)(ws + EMBB_OFF);
    float* enorm   = (float*)(ws + ENORM_OFF);
    int*   hist    = (int*)(ws + HIST_OFF);
    float* lossAcc = (float*)(ws + LOSS_OFF);
    int*   gdone   = (int*)(ws + GDONE_OFF);

    prep_emb<<<64, 256, 0, stream>>>(emb, embB, enorm, hist, lossAcc, gdone);
    vq_main<<<512, 256, 0, stream>>>(z, emb, embB, enorm, out, hist,
                                     lossAcc, gdone, out);
}